// Round 20
// baseline (76.731 us; speedup 1.0000x reference)
//
#include <hip/hip_runtime.h>

// VectorQuantizer: x[128,512,64] f32, codebook[1024,64] f32
// outputs (flat in d_out, float32): quantized[4194304], loss[1], indices[65536]
//
// R20: R19 + dual-accumulator MFMA chains. R19 falsified the epilogue-VALU
// theory (5->3 ops/key changed nothing); no-overlap pipe accounting (MFMA 10
// + VALU 20 + LDS 7 + 32 barriers 7 ~= 44 of 46us) points at intra-wave
// serialization. Remaining untried stall: each tile's 6-MFMA dependent chain
// seeded by a dependent ds_read(cnfv). Split: acc0 = cnfv-seeded 3-chain,
// acc1 = zero-seeded 3-chain (starts without waiting on cnf), key =
// acc0+acc1 (+1 VALU/key, proven irrelevant). 8 independent chains in
// flight per wave per chunk. Error budget unchanged (fp32 reorder, <=0.01
// worst case < TAU/2). Also: k3's B5 barrier removed (provably redundant).
// If flat vs R19 -> structure floor 46us confirmed, ceiling declared.

typedef __attribute__((ext_vector_type(8))) short bf16x8;
typedef __attribute__((ext_vector_type(4))) float f32x4;
typedef __attribute__((ext_vector_type(8))) unsigned short u16x8;

static constexpr int Vn    = 1024;
static constexpr int Hn    = 64;
static constexpr int Nrows = 128 * 512;          // 65536
static constexpr int QSZ   = Nrows * Hn;         // 4194304
#define TAU 0.03f
#define MARGIN 4e-3f

__device__ inline unsigned short f2bf(float f) {         // RNE fp32->bf16
  unsigned u = __float_as_uint(f);
  return (unsigned short)((u + 0x7fffu + ((u >> 16) & 1u)) >> 16);
}
__device__ inline float bf2f(unsigned short h) {
  return __uint_as_float(((unsigned)h) << 16);
}

// ---- ws layout (bytes) ----
// 0      : double cnormd[1024]      (8192)
// 8192   : double partials[256]     (2048; region reserves 32768)
// 40960  : float  cnormf[1024]      (4096)
// 307200 : int    flagCount         (8)
// 307208 : int    flagList[65536]   (262144)
// 573440 : ushort cw[1024*128]      (262144)  [ch(64)|cl(64)] per code
// 835584 : double rowKey[65536]     (524288)  per-row chosen key + ||x||^2

__global__ __launch_bounds__(256) void kC(
    const float* __restrict__ cb, unsigned short* __restrict__ cw,
    double* __restrict__ cnd, float* __restrict__ cnf,
    int* __restrict__ flagCount) {
  const int t = blockIdx.x * 256 + threadIdx.x;  // 4096 threads
  if (t == 0) *flagCount = 0;
  const int v = t >> 2, seg = t & 3;
  const float4* src = reinterpret_cast<const float4*>(cb + v * Hn + seg * 16);
  float vals[16];
  double s = 0;
#pragma unroll
  for (int q = 0; q < 4; ++q) {
    float4 f = src[q];
    vals[q * 4 + 0] = f.x; vals[q * 4 + 1] = f.y;
    vals[q * 4 + 2] = f.z; vals[q * 4 + 3] = f.w;
    s += (double)f.x * f.x + (double)f.y * f.y +
         (double)f.z * f.z + (double)f.w * f.w;
  }
  s += __shfl_xor(s, 1);                         // 4-lane group reduce
  s += __shfl_xor(s, 2);
  if (seg == 0) { cnd[v] = s; cnf[v] = (float)s; }
  u16x8 hv, hv1, lv0, lv1;
#pragma unroll
  for (int j = 0; j < 8; ++j) {
    unsigned short h = f2bf(vals[j]);
    hv[j] = h; lv0[j] = f2bf(vals[j] - bf2f(h));
    unsigned short h2 = f2bf(vals[8 + j]);
    hv1[j] = h2; lv1[j] = f2bf(vals[8 + j] - bf2f(h2));
  }
  u16x8* dh = (u16x8*)(cw + v * 128 + seg * 16);
  dh[0] = hv; dh[1] = hv1;
  u16x8* dl = (u16x8*)(cw + v * 128 + 64 + seg * 16);
  dl[0] = lv0; dl[1] = lv1;
}

// Fused MFMA screen + argmin. Block = 4 waves, each wave owns 16 rows and
// sweeps ALL 1024 codes; codebook streamed as 16 chunks of 64 codes through
// a double-buffered 16KB LDS tile. Per tile: K=192 via 2 independent 3-MFMA
// chains (acc0 = cnfv + xh.ch lo/hi + xh.cl lo; acc1 = 0 + xh.cl hi + xl.ch
// lo/hi), key = acc0+acc1. C frag: col=lane&15, row=4*(lane>>4)+reg.
__global__ __launch_bounds__(256, 4) void kMF(
    const float* __restrict__ x, const unsigned short* __restrict__ cw,
    const float* __restrict__ cnf, const float* __restrict__ cb,
    int* __restrict__ flagCount, int* __restrict__ flagList,
    float* __restrict__ out, float* __restrict__ outIdx,
    double* __restrict__ rowKey) {
  __shared__ __align__(16) char buf[2][16384];   // 64 codes x 256B, swizzled
  __shared__ __align__(16) float ldsCnf[1024];
  __shared__ double xnD[4][16];                  // per-wave row ||x||^2
  __shared__ int midx[64];                       // final idx per block row

  const int tid = threadIdx.x;
  const int lane = tid & 63;
  const int w = tid >> 6;
  const int l15 = lane & 15, g = lane >> 4;
  const int rowBase = blockIdx.x * 64 + w * 16;  // this wave's 16 rows
  const char* cwb = (const char*)cw;

  // ---- A fragments {h0,h1,l0,l1} of (-2x) for 16 rows + fp64 row norms ----
  bf16x8 A0, A1, A2, A3;
  {
    const float* xr = x + (long)(rowBase + l15) * Hn + g * 8;
    float4 fa0 = *(const float4*)(xr + 0);
    float4 fa1 = *(const float4*)(xr + 4);
    float4 fb0 = *(const float4*)(xr + 32);
    float4 fb1 = *(const float4*)(xr + 36);
    float va[8] = {fa0.x, fa0.y, fa0.z, fa0.w, fa1.x, fa1.y, fa1.z, fa1.w};
    float vb[8] = {fb0.x, fb0.y, fb0.z, fb0.w, fb1.x, fb1.y, fb1.z, fb1.w};
    double rn = 0;
#pragma unroll
    for (int j = 0; j < 8; ++j) {
      rn += (double)va[j] * va[j] + (double)vb[j] * vb[j];
      float sa = -2.0f * va[j];
      unsigned short h = f2bf(sa);
      A0[j] = (short)h;
      A2[j] = (short)f2bf(sa - bf2f(h));
      float sb = -2.0f * vb[j];
      unsigned short h2 = f2bf(sb);
      A1[j] = (short)h2;
      A3[j] = (short)f2bf(sb - bf2f(h2));
    }
    rn += __shfl_xor(rn, 16);                    // sum over g (fixed order)
    rn += __shfl_xor(rn, 32);
    if (g == 0) xnD[w][l15] = rn;                // row rowBase+l15
  }

  float b1[4], b2[4];                            // b1 packed, b2 raw
#pragma unroll
  for (int r = 0; r < 4; ++r) { b1[r] = 3.0e38f; b2[r] = 3.0e38f; }

// swizzled LDS byte offset: full 4-bit XOR -> bijective per 16-lane phase
#define SWZ(c_, u_) ((c_) * 256 + (((u_) * 16) ^ (((c_) & 15) << 4)))

  // ---- prologue: stage chunk 0 (64 codes = 16KB; 64B/thread) + cnf ----
  {
    const char* gp = cwb + tid * 64;
    float4 s0 = *(const float4*)(gp + 0),  s1 = *(const float4*)(gp + 16);
    float4 s2 = *(const float4*)(gp + 32), s3 = *(const float4*)(gp + 48);
    float4 cf = reinterpret_cast<const float4*>(cnf)[tid];
    const int c = tid >> 2;
#pragma unroll
    for (int i = 0; i < 4; ++i) {
      const int u = 4 * (tid & 3) + i;
      float4 sv = (i == 0) ? s0 : (i == 1) ? s1 : (i == 2) ? s2 : s3;
      *(float4*)(&buf[0][SWZ(c, u)]) = sv;
    }
    reinterpret_cast<float4*>(ldsCnf)[tid] = cf;
  }
  __syncthreads();

  // ---- main loop: load(next)->regs || compute(cur) ; bar ; ds_write ; bar --
  for (int ch = 0; ch < 16; ++ch) {
    float4 s0, s1, s2, s3;
    if (ch < 15) {                               // issue next-chunk loads NOW
      const char* gp = cwb + (ch + 1) * 16384 + tid * 64;
      s0 = *(const float4*)(gp + 0);   s1 = *(const float4*)(gp + 16);
      s2 = *(const float4*)(gp + 32);  s3 = *(const float4*)(gp + 48);
    }

    const char* Bb = buf[ch & 1];
#pragma unroll
    for (int tt = 0; tt < 4; ++tt) {
      const int cl = tt * 16 + l15;              // local code in chunk
      const char* cbase = Bb + cl * 256;
      const int sw = l15 << 4;                   // (cl&15)<<4 == l15<<4
      bf16x8 B0 = *(const bf16x8*)(cbase + ((16 * g) ^ sw));        // ch lo-K
      bf16x8 B1 = *(const bf16x8*)(cbase + ((64 + 16 * g) ^ sw));   // ch hi-K
      bf16x8 B2 = *(const bf16x8*)(cbase + ((128 + 16 * g) ^ sw));  // cl lo-K
      bf16x8 B3 = *(const bf16x8*)(cbase + ((192 + 16 * g) ^ sw));  // cl hi-K
      const int local6 = ch * 4 + tt;            // 6-bit per-lane code id
      const int v = ch * 64 + cl;
      const float cnfv = ldsCnf[v];
      // two independent 3-MFMA chains (acc1 starts without cnfv dependency)
      f32x4 acc0 = {cnfv, cnfv, cnfv, cnfv};
      f32x4 acc1 = {0.f, 0.f, 0.f, 0.f};
      acc1 = __builtin_amdgcn_mfma_f32_16x16x32_bf16(A1, B3, acc1, 0, 0, 0);
      acc0 = __builtin_amdgcn_mfma_f32_16x16x32_bf16(A0, B0, acc0, 0, 0, 0);
      acc1 = __builtin_amdgcn_mfma_f32_16x16x32_bf16(A2, B0, acc1, 0, 0, 0);
      acc0 = __builtin_amdgcn_mfma_f32_16x16x32_bf16(A1, B1, acc0, 0, 0, 0);
      acc1 = __builtin_amdgcn_mfma_f32_16x16x32_bf16(A3, B1, acc1, 0, 0, 0);
      acc0 = __builtin_amdgcn_mfma_f32_16x16x32_bf16(A0, B2, acc0, 0, 0, 0);
#pragma unroll
      for (int r = 0; r < 4; ++r) {
        float key = acc0[r] + acc1[r];           // = ||c||^2 - 2 x.c
        float pk = __uint_as_float(
            (__float_as_uint(key) & 0xFFFFFFC0u) | (unsigned)local6);
        b2[r] = __builtin_amdgcn_fmed3f(key, b1[r], b2[r]);  // raw 2nd-best
        b1[r] = fminf(b1[r], pk);                // packed best (idx rides)
      }
    }
    __syncthreads();                             // all waves done with buf[(ch+1)&1]
    if (ch < 15) {
      const int c = tid >> 2;
#pragma unroll
      for (int i = 0; i < 4; ++i) {
        const int u = 4 * (tid & 3) + i;
        float4 sv = (i == 0) ? s0 : (i == 1) ? s1 : (i == 2) ? s2 : s3;
        *(float4*)(&buf[(ch + 1) & 1][SWZ(c, u)]) = sv;
      }
    }
    __syncthreads();                             // next chunk visible
  }
#undef SWZ

  // ---- unpack, then merge top-2 across the 16 lanes holding each row ----
  int bi[4];
#pragma unroll
  for (int r = 0; r < 4; ++r)
    bi[r] = (int)(__float_as_uint(b1[r]) & 63u) * 16 + l15;

#pragma unroll
  for (int r = 0; r < 4; ++r) {
    float B1r = b1[r], B2r = b2[r];
    int Ir = bi[r];
#pragma unroll
    for (int m = 1; m < 16; m <<= 1) {
      float o1 = __shfl_xor(B1r, m), o2 = __shfl_xor(B2r, m);
      int oi = __shfl_xor(Ir, m);
      float worse = fmaxf(B1r, o1);
      B2r = fminf(fminf(B2r, o2), worse);
      bool take = (o1 < B1r) || (o1 == B1r && oi < Ir);
      B1r = take ? o1 : B1r;
      Ir  = take ? oi : Ir;
    }
    b1[r] = B1r; b2[r] = B2r; bi[r] = Ir;
  }

  // Writers: lane with l15==r publishes row rowBase + 4g + r.
#pragma unroll
  for (int r = 0; r < 4; ++r)
    if (l15 == r) {
      const int row = rowBase + 4 * g + r;
      outIdx[row] = (float)bi[r];
      midx[w * 16 + 4 * g + r] = bi[r];
      rowKey[row] = xnD[w][4 * g + r] + (double)b1[r];   // ||x||^2 + key
      if (b2[r] - b1[r] <= TAU) {
        int slot = atomicAdd(flagCount, 1);
        flagList[slot] = row;                    // order-independent use
      }
    }
  __syncthreads();                               // midx visible

  // ---- quantized write: 64 rows x 64 cols, coalesced; cb is L2-hot ----
  const int rbase = blockIdx.x * 64;
#pragma unroll
  for (int i = 0; i < 16; ++i) {
    const int rl = 4 * i + (tid >> 6);
    const int idx = midx[rl];
    out[(size_t)(rbase + rl) * 64 + (tid & 63)] = cb[idx * 64 + (tid & 63)];
  }
}

// Recheck flagged rows: ONE row per block. Exact-fp32 sweep (4 codes/thr),
// wave shfl min -> 4-slot merge; fp64 keys only within MARGIN of min; wave
// argmin -> merge; rewrite outIdx, rowKey, and the quantized row.
__global__ __launch_bounds__(256) void k3_recheck(
    const float* __restrict__ x, const float* __restrict__ cb,
    const double* __restrict__ cnd, const float* __restrict__ cnf,
    const int* __restrict__ flagCount, const int* __restrict__ flagList,
    float* __restrict__ out, float* __restrict__ outIdx,
    double* __restrict__ rowKey) {
  __shared__ float xs[64];
  __shared__ float sW[4];
  __shared__ double sD[4];
  __shared__ int    sI[4];
  __shared__ double sXN;
  __shared__ int    sFin;
  const int tid = threadIdx.x;
  const int lane = tid & 63;
  const int w = tid >> 6;
  const int cnt = *flagCount;

  for (int jj = blockIdx.x; jj < cnt; jj += gridDim.x) {
    const int row = flagList[jj];
    if (tid < 16)
      reinterpret_cast<float4*>(xs)[tid] =
          reinterpret_cast<const float4*>(x + (long)row * Hn)[tid];
    __syncthreads();                             // B1: xs visible

    if (w == 0) {                                // fp64 ||x||^2, fixed tree
      double v = (double)xs[lane] * (double)xs[lane];
#pragma unroll
      for (int off = 1; off < 64; off <<= 1) v += __shfl_xor(v, off);
      if (lane == 0) sXN = v;
    }

    float key32[4];
#pragma unroll
    for (int cc = 0; cc < 4; ++cc) {
      const int v = cc * 256 + tid;
      const float4* c4 = reinterpret_cast<const float4*>(cb + v * Hn);
      float d0 = 0, d1 = 0, d2 = 0, d3 = 0;
#pragma unroll
      for (int k = 0; k < 16; ++k) {
        float4 f = c4[k];
        d0 = fmaf(f.x, xs[4 * k + 0], d0);
        d1 = fmaf(f.y, xs[4 * k + 1], d1);
        d2 = fmaf(f.z, xs[4 * k + 2], d2);
        d3 = fmaf(f.w, xs[4 * k + 3], d3);
      }
      key32[cc] = cnf[v] - 2.0f * ((d0 + d1) + (d2 + d3));
    }

    float m = fminf(fminf(key32[0], key32[1]), fminf(key32[2], key32[3]));
#pragma unroll
    for (int off = 1; off < 64; off <<= 1) m = fminf(m, __shfl_xor(m, off));
    if (lane == 0) sW[w] = m;
    __syncthreads();                             // B2: sW/sXN visible
    const float m1 = fminf(fminf(sW[0], sW[1]), fminf(sW[2], sW[3]));

    double bk = 1e300;
    int bidx = 0x7FFFFFFF;
#pragma unroll
    for (int cc = 0; cc < 4; ++cc) {
      if (key32[cc] <= m1 + MARGIN) {
        const int v = cc * 256 + tid;
        const float4* c4 = reinterpret_cast<const float4*>(cb + v * Hn);
        double a0 = 0, a1 = 0, a2 = 0, a3 = 0;
#pragma unroll
        for (int k = 0; k < 16; ++k) {
          float4 f = c4[k];
          a0 += (double)f.x * (double)xs[4 * k + 0];
          a1 += (double)f.y * (double)xs[4 * k + 1];
          a2 += (double)f.z * (double)xs[4 * k + 2];
          a3 += (double)f.w * (double)xs[4 * k + 3];
        }
        double key = cnd[v] - 2.0 * ((a0 + a1) + (a2 + a3));
        if (key < bk || (key == bk && v < bidx)) { bk = key; bidx = v; }
      }
    }
#pragma unroll
    for (int off = 1; off < 64; off <<= 1) {
      double ok = __shfl_xor(bk, off);
      int oi = __shfl_xor(bidx, off);
      if (ok < bk || (ok == bk && oi < bidx)) { bk = ok; bidx = oi; }
    }
    if (lane == 0) { sD[w] = bk; sI[w] = bidx; }
    __syncthreads();                             // B3: sD/sI visible
    if (tid == 0) {
      double K = sD[0]; int I = sI[0];
#pragma unroll
      for (int q = 1; q < 4; ++q)
        if (sD[q] < K || (sD[q] == K && sI[q] < I)) { K = sD[q]; I = sI[q]; }
      outIdx[row] = (float)I;
      rowKey[row] = sXN + K;                     // exact fp64 key
      sFin = I;
    }
    __syncthreads();                             // B4: sFin visible
    if (tid < 64)                                // rewrite quantized row
      out[(size_t)row * 64 + tid] = cb[sFin * 64 + tid];
    // B5 removed: all xs readers finish before B3; B4 orders next-iter writes.
  }
}

// Loss stage 1: fixed-order fp64 reduce of rowKey (65536 doubles).
__global__ __launch_bounds__(256) void k5_loss(
    const double* __restrict__ rowKey, double* __restrict__ partials) {
  __shared__ double wsum[4];
  const int tid = threadIdx.x;
  double v = rowKey[blockIdx.x * 256 + tid];
#pragma unroll
  for (int off = 1; off < 64; off <<= 1) v += __shfl_xor(v, off);  // fixed tree
  if ((tid & 63) == 0) wsum[tid >> 6] = v;
  __syncthreads();
  if (tid == 0) partials[blockIdx.x] = (wsum[0] + wsum[1]) + (wsum[2] + wsum[3]);
}

__global__ __launch_bounds__(256) void k6_loss(const double* __restrict__ partials,
                                               float* __restrict__ out) {
  __shared__ double red[256];
  red[threadIdx.x] = partials[threadIdx.x];      // 256 partials
  __syncthreads();
  for (int s = 128; s > 0; s >>= 1) {
    if (threadIdx.x < s) red[threadIdx.x] += red[threadIdx.x + s];
    __syncthreads();
  }
  if (threadIdx.x == 0)
    out[QSZ] = (float)(1.25 * red[0] / (double)QSZ);
}

extern "C" void kernel_launch(void* const* d_in, const int* in_sizes, int n_in,
                              void* d_out, int out_size, void* d_ws, size_t ws_size,
                              hipStream_t stream) {
  const float* x  = (const float*)d_in[0];
  const float* cb = (const float*)d_in[1];
  float* out = (float*)d_out;
  char* ws = (char*)d_ws;

  double* cnd      = (double*)(ws + 0);
  double* partials = (double*)(ws + 8192);
  float*  cnf      = (float*) (ws + 40960);
  int*    flagCnt  = (int*)   (ws + 307200);
  int*    flagList = (int*)   (ws + 307208);
  unsigned short* cw = (unsigned short*)(ws + 573440);
  double* rowKey   = (double*)(ws + 835584);

  float* outIdx = out + QSZ + 1;

  kC        <<<16,   256, 0, stream>>>(cb, cw, cnd, cnf, flagCnt);
  kMF       <<<1024, 256, 0, stream>>>(x, cw, cnf, cb, flagCnt, flagList,
                                       out, outIdx, rowKey);
  k3_recheck<<<2048, 256, 0, stream>>>(x, cb, cnd, cnf, flagCnt, flagList,
                                       out, outIdx, rowKey);
  k5_loss   <<<256,  256, 0, stream>>>(rowKey, partials);
  k6_loss   <<<1,    256, 0, stream>>>(partials, out);
}

// Round 21
// 75.338 us; speedup vs baseline: 1.0185x; 1.0185x over previous
//
#include <hip/hip_runtime.h>

// VectorQuantizer: x[128,512,64] f32, codebook[1024,64] f32
// outputs (flat in d_out, float32): quantized[4194304], loss[1], indices[65536]
//
// R21 FINAL: exact R19 (best measured, 75.4us) + R20's proven-safe removal
// of k3's redundant B5 barrier. Session ceiling: kMF plateaus at 42-48us
// across 5 independent structural levers (occupancy, reg-pipelining,
// code-split, epilogue VALU, MFMA ILP); pipes <=45% busy at grid-bound
// 4 waves/SIMD. Decomposition floor ~70us incl. tail + launch overhead.
//
// Structure: kMF = MFMA screen (split-bf16 K=192, 6 MFMA/tile, C-init =
// ||c||^2, barrier-pinned reg->LDS chunk pipeline, bijective 4-bit XOR
// swizzle, packed key+index top-2) writes q + idx + rowKey; k3 rechecks
// TAU-flagged rows (fp32-exact sweep + selective fp64) -> argmin fp64-exact;
// k5/k6 reduce rowKey in fixed order -> loss fp64-deterministic.

typedef __attribute__((ext_vector_type(8))) short bf16x8;
typedef __attribute__((ext_vector_type(4))) float f32x4;
typedef __attribute__((ext_vector_type(8))) unsigned short u16x8;

static constexpr int Vn    = 1024;
static constexpr int Hn    = 64;
static constexpr int Nrows = 128 * 512;          // 65536
static constexpr int QSZ   = Nrows * Hn;         // 4194304
#define TAU 0.03f
#define MARGIN 4e-3f

__device__ inline unsigned short f2bf(float f) {         // RNE fp32->bf16
  unsigned u = __float_as_uint(f);
  return (unsigned short)((u + 0x7fffu + ((u >> 16) & 1u)) >> 16);
}
__device__ inline float bf2f(unsigned short h) {
  return __uint_as_float(((unsigned)h) << 16);
}

// ---- ws layout (bytes) ----
// 0      : double cnormd[1024]      (8192)
// 8192   : double partials[256]     (2048; region reserves 32768)
// 40960  : float  cnormf[1024]      (4096)
// 307200 : int    flagCount         (8)
// 307208 : int    flagList[65536]   (262144)
// 573440 : ushort cw[1024*128]      (262144)  [ch(64)|cl(64)] per code
// 835584 : double rowKey[65536]     (524288)  per-row chosen key + ||x||^2

__global__ __launch_bounds__(256) void kC(
    const float* __restrict__ cb, unsigned short* __restrict__ cw,
    double* __restrict__ cnd, float* __restrict__ cnf,
    int* __restrict__ flagCount) {
  const int t = blockIdx.x * 256 + threadIdx.x;  // 4096 threads
  if (t == 0) *flagCount = 0;
  const int v = t >> 2, seg = t & 3;
  const float4* src = reinterpret_cast<const float4*>(cb + v * Hn + seg * 16);
  float vals[16];
  double s = 0;
#pragma unroll
  for (int q = 0; q < 4; ++q) {
    float4 f = src[q];
    vals[q * 4 + 0] = f.x; vals[q * 4 + 1] = f.y;
    vals[q * 4 + 2] = f.z; vals[q * 4 + 3] = f.w;
    s += (double)f.x * f.x + (double)f.y * f.y +
         (double)f.z * f.z + (double)f.w * f.w;
  }
  s += __shfl_xor(s, 1);                         // 4-lane group reduce
  s += __shfl_xor(s, 2);
  if (seg == 0) { cnd[v] = s; cnf[v] = (float)s; }
  u16x8 hv, hv1, lv0, lv1;
#pragma unroll
  for (int j = 0; j < 8; ++j) {
    unsigned short h = f2bf(vals[j]);
    hv[j] = h; lv0[j] = f2bf(vals[j] - bf2f(h));
    unsigned short h2 = f2bf(vals[8 + j]);
    hv1[j] = h2; lv1[j] = f2bf(vals[8 + j] - bf2f(h2));
  }
  u16x8* dh = (u16x8*)(cw + v * 128 + seg * 16);
  dh[0] = hv; dh[1] = hv1;
  u16x8* dl = (u16x8*)(cw + v * 128 + 64 + seg * 16);
  dl[0] = lv0; dl[1] = lv1;
}

// Fused MFMA screen + argmin. Block = 4 waves, each wave owns 16 rows and
// sweeps ALL 1024 codes; codebook streamed as 16 chunks of 64 codes through
// a double-buffered 16KB LDS tile. Per tile: K=192 via 6 MFMA, C-init =
// ||c||^2 -> acc = key. C frag: col=lane&15, row=4*(lane>>4)+reg (verified).
__global__ __launch_bounds__(256, 4) void kMF(
    const float* __restrict__ x, const unsigned short* __restrict__ cw,
    const float* __restrict__ cnf, const float* __restrict__ cb,
    int* __restrict__ flagCount, int* __restrict__ flagList,
    float* __restrict__ out, float* __restrict__ outIdx,
    double* __restrict__ rowKey) {
  __shared__ __align__(16) char buf[2][16384];   // 64 codes x 256B, swizzled
  __shared__ __align__(16) float ldsCnf[1024];
  __shared__ double xnD[4][16];                  // per-wave row ||x||^2
  __shared__ int midx[64];                       // final idx per block row

  const int tid = threadIdx.x;
  const int lane = tid & 63;
  const int w = tid >> 6;
  const int l15 = lane & 15, g = lane >> 4;
  const int rowBase = blockIdx.x * 64 + w * 16;  // this wave's 16 rows
  const char* cwb = (const char*)cw;

  // ---- A fragments {h0,h1,l0,l1} of (-2x) for 16 rows + fp64 row norms ----
  bf16x8 A0, A1, A2, A3;
  {
    const float* xr = x + (long)(rowBase + l15) * Hn + g * 8;
    float4 fa0 = *(const float4*)(xr + 0);
    float4 fa1 = *(const float4*)(xr + 4);
    float4 fb0 = *(const float4*)(xr + 32);
    float4 fb1 = *(const float4*)(xr + 36);
    float va[8] = {fa0.x, fa0.y, fa0.z, fa0.w, fa1.x, fa1.y, fa1.z, fa1.w};
    float vb[8] = {fb0.x, fb0.y, fb0.z, fb0.w, fb1.x, fb1.y, fb1.z, fb1.w};
    double rn = 0;
#pragma unroll
    for (int j = 0; j < 8; ++j) {
      rn += (double)va[j] * va[j] + (double)vb[j] * vb[j];
      float sa = -2.0f * va[j];
      unsigned short h = f2bf(sa);
      A0[j] = (short)h;
      A2[j] = (short)f2bf(sa - bf2f(h));
      float sb = -2.0f * vb[j];
      unsigned short h2 = f2bf(sb);
      A1[j] = (short)h2;
      A3[j] = (short)f2bf(sb - bf2f(h2));
    }
    rn += __shfl_xor(rn, 16);                    // sum over g (fixed order)
    rn += __shfl_xor(rn, 32);
    if (g == 0) xnD[w][l15] = rn;                // row rowBase+l15
  }

  float b1[4], b2[4];                            // b1 packed, b2 raw
#pragma unroll
  for (int r = 0; r < 4; ++r) { b1[r] = 3.0e38f; b2[r] = 3.0e38f; }

// swizzled LDS byte offset: full 4-bit XOR -> bijective per 16-lane phase
#define SWZ(c_, u_) ((c_) * 256 + (((u_) * 16) ^ (((c_) & 15) << 4)))

  // ---- prologue: stage chunk 0 (64 codes = 16KB; 64B/thread) + cnf ----
  {
    const char* gp = cwb + tid * 64;
    float4 s0 = *(const float4*)(gp + 0),  s1 = *(const float4*)(gp + 16);
    float4 s2 = *(const float4*)(gp + 32), s3 = *(const float4*)(gp + 48);
    float4 cf = reinterpret_cast<const float4*>(cnf)[tid];
    const int c = tid >> 2;
#pragma unroll
    for (int i = 0; i < 4; ++i) {
      const int u = 4 * (tid & 3) + i;
      float4 sv = (i == 0) ? s0 : (i == 1) ? s1 : (i == 2) ? s2 : s3;
      *(float4*)(&buf[0][SWZ(c, u)]) = sv;
    }
    reinterpret_cast<float4*>(ldsCnf)[tid] = cf;
  }
  __syncthreads();

  // ---- main loop: load(next)->regs || compute(cur) ; bar ; ds_write ; bar --
  for (int ch = 0; ch < 16; ++ch) {
    float4 s0, s1, s2, s3;
    if (ch < 15) {                               // issue next-chunk loads NOW
      const char* gp = cwb + (ch + 1) * 16384 + tid * 64;
      s0 = *(const float4*)(gp + 0);   s1 = *(const float4*)(gp + 16);
      s2 = *(const float4*)(gp + 32);  s3 = *(const float4*)(gp + 48);
    }

    const char* Bb = buf[ch & 1];
#pragma unroll
    for (int tt = 0; tt < 4; ++tt) {
      const int cl = tt * 16 + l15;              // local code in chunk
      const char* cbase = Bb + cl * 256;
      const int sw = l15 << 4;                   // (cl&15)<<4 == l15<<4
      bf16x8 B0 = *(const bf16x8*)(cbase + ((16 * g) ^ sw));        // ch lo-K
      bf16x8 B1 = *(const bf16x8*)(cbase + ((64 + 16 * g) ^ sw));   // ch hi-K
      bf16x8 B2 = *(const bf16x8*)(cbase + ((128 + 16 * g) ^ sw));  // cl lo-K
      bf16x8 B3 = *(const bf16x8*)(cbase + ((192 + 16 * g) ^ sw));  // cl hi-K
      const int local6 = ch * 4 + tt;            // 6-bit per-lane code id
      const int v = ch * 64 + cl;
      const float cnfv = ldsCnf[v];
      f32x4 acc = {cnfv, cnfv, cnfv, cnfv};      // C-init = ||c||^2
      acc = __builtin_amdgcn_mfma_f32_16x16x32_bf16(A0, B0, acc, 0, 0, 0);
      acc = __builtin_amdgcn_mfma_f32_16x16x32_bf16(A1, B1, acc, 0, 0, 0);
      acc = __builtin_amdgcn_mfma_f32_16x16x32_bf16(A0, B2, acc, 0, 0, 0);
      acc = __builtin_amdgcn_mfma_f32_16x16x32_bf16(A1, B3, acc, 0, 0, 0);
      acc = __builtin_amdgcn_mfma_f32_16x16x32_bf16(A2, B0, acc, 0, 0, 0);
      acc = __builtin_amdgcn_mfma_f32_16x16x32_bf16(A3, B1, acc, 0, 0, 0);
#pragma unroll
      for (int r = 0; r < 4; ++r) {
        float key = acc[r];                      // = ||c||^2 - 2 x.c
        float pk = __uint_as_float(
            (__float_as_uint(key) & 0xFFFFFFC0u) | (unsigned)local6);
        b2[r] = __builtin_amdgcn_fmed3f(key, b1[r], b2[r]);  // raw 2nd-best
        b1[r] = fminf(b1[r], pk);                // packed best (idx rides)
      }
    }
    __syncthreads();                             // all waves done with buf[(ch+1)&1]
    if (ch < 15) {
      const int c = tid >> 2;
#pragma unroll
      for (int i = 0; i < 4; ++i) {
        const int u = 4 * (tid & 3) + i;
        float4 sv = (i == 0) ? s0 : (i == 1) ? s1 : (i == 2) ? s2 : s3;
        *(float4*)(&buf[(ch + 1) & 1][SWZ(c, u)]) = sv;
      }
    }
    __syncthreads();                             // next chunk visible
  }
#undef SWZ

  // ---- unpack, then merge top-2 across the 16 lanes holding each row ----
  int bi[4];
#pragma unroll
  for (int r = 0; r < 4; ++r)
    bi[r] = (int)(__float_as_uint(b1[r]) & 63u) * 16 + l15;

#pragma unroll
  for (int r = 0; r < 4; ++r) {
    float B1r = b1[r], B2r = b2[r];
    int Ir = bi[r];
#pragma unroll
    for (int m = 1; m < 16; m <<= 1) {
      float o1 = __shfl_xor(B1r, m), o2 = __shfl_xor(B2r, m);
      int oi = __shfl_xor(Ir, m);
      float worse = fmaxf(B1r, o1);
      B2r = fminf(fminf(B2r, o2), worse);
      bool take = (o1 < B1r) || (o1 == B1r && oi < Ir);
      B1r = take ? o1 : B1r;
      Ir  = take ? oi : Ir;
    }
    b1[r] = B1r; b2[r] = B2r; bi[r] = Ir;
  }

  // Writers: lane with l15==r publishes row rowBase + 4g + r.
#pragma unroll
  for (int r = 0; r < 4; ++r)
    if (l15 == r) {
      const int row = rowBase + 4 * g + r;
      outIdx[row] = (float)bi[r];
      midx[w * 16 + 4 * g + r] = bi[r];
      rowKey[row] = xnD[w][4 * g + r] + (double)b1[r];   // ||x||^2 + key
      if (b2[r] - b1[r] <= TAU) {
        int slot = atomicAdd(flagCount, 1);
        flagList[slot] = row;                    // order-independent use
      }
    }
  __syncthreads();                               // midx visible

  // ---- quantized write: 64 rows x 64 cols, coalesced; cb is L2-hot ----
  const int rbase = blockIdx.x * 64;
#pragma unroll
  for (int i = 0; i < 16; ++i) {
    const int rl = 4 * i + (tid >> 6);
    const int idx = midx[rl];
    out[(size_t)(rbase + rl) * 64 + (tid & 63)] = cb[idx * 64 + (tid & 63)];
  }
}

// Recheck flagged rows: ONE row per block. Exact-fp32 sweep (4 codes/thr),
// wave shfl min -> 4-slot merge; fp64 keys only within MARGIN of min; wave
// argmin -> merge; rewrite outIdx, rowKey, and the quantized row.
__global__ __launch_bounds__(256) void k3_recheck(
    const float* __restrict__ x, const float* __restrict__ cb,
    const double* __restrict__ cnd, const float* __restrict__ cnf,
    const int* __restrict__ flagCount, const int* __restrict__ flagList,
    float* __restrict__ out, float* __restrict__ outIdx,
    double* __restrict__ rowKey) {
  __shared__ float xs[64];
  __shared__ float sW[4];
  __shared__ double sD[4];
  __shared__ int    sI[4];
  __shared__ double sXN;
  __shared__ int    sFin;
  const int tid = threadIdx.x;
  const int lane = tid & 63;
  const int w = tid >> 6;
  const int cnt = *flagCount;

  for (int jj = blockIdx.x; jj < cnt; jj += gridDim.x) {
    const int row = flagList[jj];
    if (tid < 16)
      reinterpret_cast<float4*>(xs)[tid] =
          reinterpret_cast<const float4*>(x + (long)row * Hn)[tid];
    __syncthreads();                             // B1: xs visible

    if (w == 0) {                                // fp64 ||x||^2, fixed tree
      double v = (double)xs[lane] * (double)xs[lane];
#pragma unroll
      for (int off = 1; off < 64; off <<= 1) v += __shfl_xor(v, off);
      if (lane == 0) sXN = v;
    }

    float key32[4];
#pragma unroll
    for (int cc = 0; cc < 4; ++cc) {
      const int v = cc * 256 + tid;
      const float4* c4 = reinterpret_cast<const float4*>(cb + v * Hn);
      float d0 = 0, d1 = 0, d2 = 0, d3 = 0;
#pragma unroll
      for (int k = 0; k < 16; ++k) {
        float4 f = c4[k];
        d0 = fmaf(f.x, xs[4 * k + 0], d0);
        d1 = fmaf(f.y, xs[4 * k + 1], d1);
        d2 = fmaf(f.z, xs[4 * k + 2], d2);
        d3 = fmaf(f.w, xs[4 * k + 3], d3);
      }
      key32[cc] = cnf[v] - 2.0f * ((d0 + d1) + (d2 + d3));
    }

    float m = fminf(fminf(key32[0], key32[1]), fminf(key32[2], key32[3]));
#pragma unroll
    for (int off = 1; off < 64; off <<= 1) m = fminf(m, __shfl_xor(m, off));
    if (lane == 0) sW[w] = m;
    __syncthreads();                             // B2: sW/sXN visible
    const float m1 = fminf(fminf(sW[0], sW[1]), fminf(sW[2], sW[3]));

    double bk = 1e300;
    int bidx = 0x7FFFFFFF;
#pragma unroll
    for (int cc = 0; cc < 4; ++cc) {
      if (key32[cc] <= m1 + MARGIN) {
        const int v = cc * 256 + tid;
        const float4* c4 = reinterpret_cast<const float4*>(cb + v * Hn);
        double a0 = 0, a1 = 0, a2 = 0, a3 = 0;
#pragma unroll
        for (int k = 0; k < 16; ++k) {
          float4 f = c4[k];
          a0 += (double)f.x * (double)xs[4 * k + 0];
          a1 += (double)f.y * (double)xs[4 * k + 1];
          a2 += (double)f.z * (double)xs[4 * k + 2];
          a3 += (double)f.w * (double)xs[4 * k + 3];
        }
        double key = cnd[v] - 2.0 * ((a0 + a1) + (a2 + a3));
        if (key < bk || (key == bk && v < bidx)) { bk = key; bidx = v; }
      }
    }
#pragma unroll
    for (int off = 1; off < 64; off <<= 1) {
      double ok = __shfl_xor(bk, off);
      int oi = __shfl_xor(bidx, off);
      if (ok < bk || (ok == bk && oi < bidx)) { bk = ok; bidx = oi; }
    }
    if (lane == 0) { sD[w] = bk; sI[w] = bidx; }
    __syncthreads();                             // B3: sD/sI visible
    if (tid == 0) {
      double K = sD[0]; int I = sI[0];
#pragma unroll
      for (int q = 1; q < 4; ++q)
        if (sD[q] < K || (sD[q] == K && sI[q] < I)) { K = sD[q]; I = sI[q]; }
      outIdx[row] = (float)I;
      rowKey[row] = sXN + K;                     // exact fp64 key
      sFin = I;
    }
    __syncthreads();                             // B4: sFin visible
    if (tid < 64)                                // rewrite quantized row
      out[(size_t)row * 64 + tid] = cb[sFin * 64 + tid];
    // B5 removed: all xs readers finish before B3; B4 orders next-iter writes.
  }
}

// Loss stage 1: fixed-order fp64 reduce of rowKey (65536 doubles).
__global__ __launch_bounds__(256) void k5_loss(
    const double* __restrict__ rowKey, double* __restrict__ partials) {
  __shared__ double wsum[4];
  const int tid = threadIdx.x;
  double v = rowKey[blockIdx.x * 256 + tid];
#pragma unroll
  for (int off = 1; off < 64; off <<= 1) v += __shfl_xor(v, off);  // fixed tree
  if ((tid & 63) == 0) wsum[tid >> 6] = v;
  __syncthreads();
  if (tid == 0) partials[blockIdx.x] = (wsum[0] + wsum[1]) + (wsum[2] + wsum[3]);
}

__global__ __launch_bounds__(256) void k6_loss(const double* __restrict__ partials,
                                               float* __restrict__ out) {
  __shared__ double red[256];
  red[threadIdx.x] = partials[threadIdx.x];      // 256 partials
  __syncthreads();
  for (int s = 128; s > 0; s >>= 1) {
    if (threadIdx.x < s) red[threadIdx.x] += red[threadIdx.x + s];
    __syncthreads();
  }
  if (threadIdx.x == 0)
    out[QSZ] = (float)(1.25 * red[0] / (double)QSZ);
}

extern "C" void kernel_launch(void* const* d_in, const int* in_sizes, int n_in,
                              void* d_out, int out_size, void* d_ws, size_t ws_size,
                              hipStream_t stream) {
  const float* x  = (const float*)d_in[0];
  const float* cb = (const float*)d_in[1];
  float* out = (float*)d_out;
  char* ws = (char*)d_ws;

  double* cnd      = (double*)(ws + 0);
  double* partials = (double*)(ws + 8192);
  float*  cnf      = (float*) (ws + 40960);
  int*    flagCnt  = (int*)   (ws + 307200);
  int*    flagList = (int*)   (ws + 307208);
  unsigned short* cw = (unsigned short*)(ws + 573440);
  double* rowKey   = (double*)(ws + 835584);

  float* outIdx = out + QSZ + 1;

  kC        <<<16,   256, 0, stream>>>(cb, cw, cnd, cnf, flagCnt);
  kMF       <<<1024, 256, 0, stream>>>(x, cw, cnf, cb, flagCnt, flagList,
                                       out, outIdx, rowKey);
  k3_recheck<<<2048, 256, 0, stream>>>(x, cb, cnd, cnf, flagCnt, flagList,
                                       out, outIdx, rowKey);
  k5_loss   <<<256,  256, 0, stream>>>(rowKey, partials);
  k6_loss   <<<1,    256, 0, stream>>>(partials, out);
}